// Round 4
// baseline (6192.236 us; speedup 1.0000x reference)
//
#include <hip/hip_runtime.h>
#include <hip/hip_bf16.h>
#include <math.h>

#define B 512
#define N 50
#define D 768
#define G4 3072
#define KCAT 1536       // concat K for fused step GEMM: [Whh | Wih]
#define BN (B*N)        // 25600
#define FLAT (N*D)      // 38400
#define KC 1536         // fcross K (vsum|asum concat)
#define CCH 6400        // floats per egce chunk = 128 channels x 50

typedef __hip_bfloat16 bf16;
typedef short short8 __attribute__((ext_vector_type(8)));
typedef float floatx4 __attribute__((ext_vector_type(4)));

__device__ __forceinline__ float sigf(float x){ return 1.0f/(1.0f+expf(-x)); }
__device__ __forceinline__ float u2f(unsigned short u){ return __uint_as_float(((unsigned int)u)<<16); }
__device__ __forceinline__ unsigned short f2u(float f){ bf16 h=__float2bfloat16(f); return *(unsigned short*)&h; }

// ---- EGCE fused: coalesced chunked GAP + gates + gated v/a sums (one block/batch) --
__global__ __launch_bounds__(256) void egce_fused(
    const float* __restrict__ text, const int* __restrict__ vid, const int* __restrict__ aid,
    const float* __restrict__ vemb, const float* __restrict__ aemb, const float* __restrict__ egw,
    float* __restrict__ att_t, unsigned short* __restrict__ catAB){
  __shared__ float buf[CCH];
  __shared__ float gt[D+2], gv[D+2], ga[D+2];
  __shared__ float attvS[D], attaS[D];
  __shared__ int vidS[N], aidS[N];
  int b=blockIdx.x, tid=threadIdx.x;
  if(tid<N){ vidS[tid]=vid[b*N+tid]; aidS[tid]=aid[b*N+tid]; }
  if(tid==0){ gt[0]=gv[0]=ga[0]=0.f; gt[D+1]=gv[D+1]=ga[D+1]=0.f; }
  __syncthreads();
  const float* tb = text + (size_t)b*FLAT;
  for(int c=0;c<6;c++){
    int j0=c*CCH;
    for(int it=0;it<25;it++) buf[it*256+tid]=tb[j0+it*256+tid];
    __syncthreads();
    if(tid<128){ float s=0.f; for(int p=0;p<50;p++) s+=buf[tid*50+p]; gt[c*128+tid+1]=s*(1.f/50.f); }
    __syncthreads();
    for(int it=0;it<25;it++){ int j=j0+it*256+tid; int n=j/D, d=j-n*D;
      float v=vemb[vidS[n]*D+d]; buf[it*256+tid]=v>0.f?v:0.f; }
    __syncthreads();
    if(tid<128){ float s=0.f; for(int p=0;p<50;p++) s+=buf[tid*50+p]; gv[c*128+tid+1]=s*(1.f/50.f); }
    __syncthreads();
    for(int it=0;it<25;it++){ int j=j0+it*256+tid; int n=j/D, d=j-n*D;
      buf[it*256+tid]=aemb[aidS[n]*D+d]; }
    __syncthreads();
    if(tid<128){ float s=0.f; for(int p=0;p<50;p++) s+=buf[tid*50+p]; ga[c*128+tid+1]=s*(1.f/50.f); }
    __syncthreads();
  }
  float w0=egw[0],w1=egw[1],w2=egw[2];
  for(int ch=tid;ch<D;ch+=256){
    att_t[(size_t)b*D+ch]=sigf(w0*gt[ch]+w1*gt[ch+1]+w2*gt[ch+2]);
    attvS[ch]=sigf(w0*gv[ch]+w1*gv[ch+1]+w2*gv[ch+2]);
    attaS[ch]=sigf(w0*ga[ch]+w1*ga[ch+1]+w2*ga[ch+2]);
  }
  __syncthreads();
  float va[3]={0,0,0}, aa[3]={0,0,0};
  for(int n=0;n<N;n++){
    int idv=vidS[n], ida=aidS[n];
    #pragma unroll
    for(int q=0;q<3;q++){
      int d=q*256+tid;
      int ch=(n*D+d)/50;
      float vv=vemb[idv*D+d]; vv=vv>0.f?vv:0.f;
      va[q]+=vv*attvS[ch];
      aa[q]+=aemb[ida*D+d]*attaS[ch];
    }
  }
  for(int q=0;q<3;q++){
    int d=q*256+tid;
    catAB[(size_t)b*KC+d]    =f2u(va[q]);
    catAB[(size_t)b*KC+D+d]  =f2u(aa[q]);
  }
}

// ---- weight prep: concat [Whh | Wih] rows, gate-interleave n'=dg*4+g (bf16) --------
__global__ __launch_bounds__(256) void prep_weights(
    const float* __restrict__ Wih, const float* __restrict__ Whh,
    const float* __restrict__ bih, const float* __restrict__ bhh,
    unsigned short* __restrict__ Wcat, float* __restrict__ bsum){
  int np = blockIdx.x;
  int dg = np>>2, g = np&3;
  size_t src = (size_t)(g*D+dg)*D;
  for(int k=threadIdx.x;k<D;k+=256){
    Wcat[(size_t)np*KCAT + k]     = f2u(Whh[src+k]);
    Wcat[(size_t)np*KCAT + D + k] = f2u(Wih[src+k]);
  }
  if(threadIdx.x==0) bsum[np] = bih[g*D+dg] + bhh[g*D+dg];
}

// ---- fcross weight prep ------------------------------------------------------------
__global__ __launch_bounds__(256) void prep_fcross(
    const float* __restrict__ vW, const float* __restrict__ vb,
    unsigned short* __restrict__ WcB, float* __restrict__ fb){
  int n = blockIdx.x;
  const float* W0 = vW; const float* W1 = vW + D*D; const float* W2 = vW + 2*D*D;
  for(int k=threadIdx.x;k<D;k+=256){
    WcB[(size_t)n*KC + k]     = f2u(W0[(size_t)n*D+k]);
    WcB[(size_t)n*KC + D + k] = f2u(W1[(size_t)n*D+k] + W2[(size_t)n*D+k]);
  }
  if(threadIdx.x==0) fb[n] = 50.f*(vb[n]+vb[D+n]+vb[2*D+n]);
}

// ---- fcross MFMA -------------------------------------------------------------------
__global__ __launch_bounds__(256) void fcross_mfma(
    const unsigned short* __restrict__ catAB, const unsigned short* __restrict__ WcB,
    const float* __restrict__ fb, float* __restrict__ fcross){
  __shared__ unsigned short Ash[32*40];
  __shared__ unsigned short Bsh[64*40];
  int tid=threadIdx.x;
  int bx=blockIdx.x, by=blockIdx.y;
  int lane=tid&63, w=tid>>6;
  int l15=lane&15, lq=lane>>4;
  int arow=tid>>3, aseg=(tid&7)*4;
  int brow=tid>>2, bseg=(tid&3)*8;
  floatx4 acc0={},acc1={};
  const unsigned short* aG = catAB + (size_t)(by*32 + arow)*KC + aseg;
  const unsigned short* bG = WcB   + (size_t)(bx*64 + brow)*KC + bseg;
  for(int k0=0;k0<KC;k0+=32){
    *(uint2*)&Ash[arow*40 + aseg] = *(const uint2*)(aG + k0);
    *(uint4*)&Bsh[brow*40 + bseg] = *(const uint4*)(bG + k0);
    __syncthreads();
    short8 a0=*(const short8*)&Ash[l15*40 + lq*8];
    short8 a1=*(const short8*)&Ash[(16+l15)*40 + lq*8];
    short8 bb=*(const short8*)&Bsh[(w*16 + l15)*40 + lq*8];
    acc0=__builtin_amdgcn_mfma_f32_16x16x32_bf16(a0,bb,acc0,0,0,0);
    acc1=__builtin_amdgcn_mfma_f32_16x16x32_bf16(a1,bb,acc1,0,0,0);
    __syncthreads();
  }
  int n = bx*64 + w*16 + l15;
  float bias = fb[n];
  #pragma unroll
  for(int r=0;r<4;r++){
    int m0 = by*32 + lq*4 + r;
    fcross[(size_t)m0*D + n]      = (acc0[r] + bias)*(1.f/3.f);
    fcross[(size_t)(m0+16)*D + n] = (acc1[r] + bias)*(1.f/3.f);
  }
}

// ---- fused pre-LN + LayerNorm ------------------------------------------------------
__global__ __launch_bounds__(256) void fuse_ln(
    const float* __restrict__ text, const float* __restrict__ att_t,
    const float* __restrict__ fcross, const float* __restrict__ lng,
    const float* __restrict__ lnb, bf16* __restrict__ shift){
  int row = blockIdx.x;
  int b = row/N, n = row - b*N;
  int tid=threadIdx.x;
  float v[3];
  for(int q=0;q<3;q++){
    int d=q*256+tid;
    int ch=(n*D+d)/50;
    v[q] = text[(size_t)row*D+d]*att_t[(size_t)b*D+ch] + fcross[(size_t)b*D+d];
  }
  __shared__ float red[256];
  red[tid]=v[0]+v[1]+v[2]; __syncthreads();
  for(int st=128;st>0;st>>=1){ if(tid<st) red[tid]+=red[tid+st]; __syncthreads(); }
  float m = red[0]*(1.f/768.f);
  __syncthreads();
  float s2=0.f;
  for(int q=0;q<3;q++){ float dl=v[q]-m; s2+=dl*dl; }
  red[tid]=s2; __syncthreads();
  for(int st=128;st>0;st>>=1){ if(tid<st) red[tid]+=red[tid+st]; __syncthreads(); }
  float var = red[0]*(1.f/768.f);
  float rs = 1.f/sqrtf(var+1e-5f);
  for(int q=0;q<3;q++){
    int d=q*256+tid;
    shift[(size_t)row*D+d]=__float2bfloat16((v[q]-m)*rs*lng[d]+lnb[d]);
  }
}

// ---------------- barrier flag init -------------------------------------------------
__global__ __launch_bounds__(256) void zero_bar(int* __restrict__ bar){
  bar[blockIdx.x*256 + threadIdx.x] = 0;
}

// ---- persistent fused LSTM: all 50 steps in ONE launch -------------------------------
// Step body = R3's proven lstm_fused (zero-conflict stride-40 LDS, dbuf, 1 barrier/iter,
// operand-swapped epilogue). Persistence adds: c-state in registers, W L2-hot across
// steps, no launch/ramp overhead. Grid 768 = exactly 3 blocks/CU (launch_bounds(256,3);
// LDS 30KB*3=90KB<=160KB) -> all blocks co-resident; grid barrier = R1-validated
// flag-array protocol (release store + wave-0 poll + fences), scaled to 768 flags.
__global__ __launch_bounds__(256,3) void lstm_persist(
    const unsigned short* __restrict__ shift, const unsigned short* __restrict__ Wcat,
    const float* __restrict__ bsum, unsigned short* __restrict__ hA0,
    unsigned short* __restrict__ hA1,
    const float* __restrict__ text, const float* __restrict__ att_t,
    float* __restrict__ out, int* __restrict__ bar){
  __shared__ unsigned short Ab[2][64*40];    // [buf][kh*32+row][40]
  __shared__ unsigned short Bb[2][128*40];   // [buf][kh*64+row][40]
  const int tid=threadIdx.x;
  // ---- XCD-bijective decode: 8 XCDs x (6 bx panels x 16 by) ----
  const int id = blockIdx.x;
  const int xcd = id & 7;
  const int j = id >> 3;                 // 0..95 within XCD
  const int bx = xcd*6 + (j>>4);         // 0..47
  const int by = j & 15;                 // 0..15
  const int lane=tid&63, w=tid>>6, l15=lane&15, lq=lane>>4;

  // ---- staging maps (uint4 = 8 shorts per slot) ----
  const int sra = tid>>2, ca=(tid&3)*8;        // A: 64 subrows x 4 segs = 256 slots
  const int arow = sra&31, ah = sra>>5;
  const int dA = sra*40 + ca;
  const int b_a = by*32 + arow;
  const size_t hOff = (size_t)b_a*D + ah*32 + ca;

  const int sr0 = tid>>2,        c0=(tid&3)*8;       // B slot 0: subrows 0..63 (kh=0)
  const int sr1 = (tid+256)>>2,  c1=(tid&3)*8;       // B slot 1: subrows 64..127 (kh=1)
  const int br0 = sr0&63, bh0 = sr0>>6;
  const int br1 = sr1&63, bh1 = sr1>>6;
  const unsigned short* bThr0 = Wcat + (size_t)(bx*64+br0)*KCAT + bh0*32 + c0;
  const unsigned short* bThr1 = Wcat + (size_t)(bx*64+br1)*KCAT + bh1*32 + c1;
  const int dB0 = sr0*40 + c0, dB1 = sr1*40 + c1;

  // ---- epilogue constants ----
  const int nb = bx*64 + w*16 + lq*4;
  const int dg = nb>>2;
  const floatx4 bs = *(const floatx4*)&bsum[nb];
  const int b0e = by*32 + l15;           // mf=0 batch row
  const int b1e = b0e + 16;              // mf=1 batch row
  float cst0 = 0.f, cst1 = 0.f;          // c-state in registers for all 50 steps

  #pragma unroll 1
  for(int t=0; t<50; ++t){
    const unsigned short* hprev = (t&1) ? hA1 : hA0;
    unsigned short* hnext = (t&1) ? hA0 : hA1;
    const unsigned short* hThr = hprev + hOff;
    const unsigned short* xThr = shift + ((size_t)b_a*N + t)*D + ah*32 + ca;

    const int kbase  = t ? 0 : 768;      // t=0: h is zero -> skip Whh half
    const int nIters = t ? 24 : 12;

    floatx4 acc0={}, acc1={};

    // prologue: stage iter 0 into buf 0
    {
      const unsigned short* ap = (kbase<768) ? (hThr + kbase) : (xThr + (kbase-768));
      uint4 pA  = *(const uint4*)ap;
      uint4 pB0 = *(const uint4*)(bThr0 + kbase);
      uint4 pB1 = *(const uint4*)(bThr1 + kbase);
      *(uint4*)&Ab[0][dA]  = pA;
      *(uint4*)&Bb[0][dB0] = pB0;
      *(uint4*)&Bb[0][dB1] = pB1;
    }
    __syncthreads();

    #pragma unroll 2
    for(int it=0; it<nIters; ++it){
      const int cur = it&1;
      uint4 nA, nB0, nB1;
      const bool more = (it+1 < nIters);
      if(more){
        int kg = kbase + (it+1)*64;
        const unsigned short* ap = (kg<768) ? (hThr + kg) : (xThr + (kg-768));
        nA  = *(const uint4*)ap;
        nB0 = *(const uint4*)(bThr0 + kg);
        nB1 = *(const uint4*)(bThr1 + kg);
      }
      short8 Wf0 = *(const short8*)&Bb[cur][(w*16+l15)*40 + lq*8];
      short8 Wf1 = *(const short8*)&Bb[cur][(64 + w*16+l15)*40 + lq*8];
      short8 X00 = *(const short8*)&Ab[cur][(l15)*40 + lq*8];
      short8 X10 = *(const short8*)&Ab[cur][(16+l15)*40 + lq*8];
      short8 X01 = *(const short8*)&Ab[cur][(32+l15)*40 + lq*8];
      short8 X11 = *(const short8*)&Ab[cur][(48+l15)*40 + lq*8];
      acc0 = __builtin_amdgcn_mfma_f32_16x16x32_bf16(Wf0, X00, acc0, 0,0,0);
      acc1 = __builtin_amdgcn_mfma_f32_16x16x32_bf16(Wf0, X10, acc1, 0,0,0);
      acc0 = __builtin_amdgcn_mfma_f32_16x16x32_bf16(Wf1, X01, acc0, 0,0,0);
      acc1 = __builtin_amdgcn_mfma_f32_16x16x32_bf16(Wf1, X11, acc1, 0,0,0);
      if(more){
        *(uint4*)&Ab[cur^1][dA]  = nA;
        *(uint4*)&Bb[cur^1][dB0] = nB0;
        *(uint4*)&Bb[cur^1][dB1] = nB1;
      }
      __syncthreads();
    }

    // ---- epilogue: gates -> c,h (c in regs); fused residual out-write --------------
    {
      float gi=acc0[0]+bs[0], gf=acc0[1]+bs[1], gg=acc0[2]+bs[2], go=acc0[3]+bs[3];
      float cn = sigf(gf)*cst0 + sigf(gi)*tanhf(gg);
      float hn = sigf(go)*tanhf(cn);
      cst0 = cn;
      hnext[(size_t)b0e*D+dg] = f2u(hn);
      int ch = (t*D+dg)/50;
      size_t oi = ((size_t)b0e*N + t)*D + dg;
      out[oi] = hn + text[oi]*att_t[(size_t)b0e*D+ch];
    }
    {
      float gi=acc1[0]+bs[0], gf=acc1[1]+bs[1], gg=acc1[2]+bs[2], go=acc1[3]+bs[3];
      float cn = sigf(gf)*cst1 + sigf(gi)*tanhf(gg);
      float hn = sigf(go)*tanhf(cn);
      cst1 = cn;
      hnext[(size_t)b1e*D+dg] = f2u(hn);
      int ch = (t*D+dg)/50;
      size_t oi = ((size_t)b1e*N + t)*D + dg;
      out[oi] = hn + text[oi]*att_t[(size_t)b1e*D+ch];
    }

    // ---- grid barrier (R1-validated protocol, 768 flags) ---------------------------
    if(t < 49){
      __syncthreads();                        // drains vmcnt: h stores in L2
      if(tid == 0){
        __threadfence();                      // publish this block's stores agent-wide
        __hip_atomic_store(&bar[id], t+1, __ATOMIC_RELEASE, __HIP_MEMORY_SCOPE_AGENT);
      }
      if(w == 0){                             // wave 0 polls all 768 arrival flags
        #pragma unroll
        for(int q=0; q<12; ++q){
          const int fi = q*64 + lane;
          while(__hip_atomic_load(&bar[fi], __ATOMIC_RELAXED, __HIP_MEMORY_SCOPE_AGENT) < t+1)
            __builtin_amdgcn_s_sleep(1);
        }
        __threadfence();                      // acquire: invalidate stale h lines
      }
      __syncthreads();
      __threadfence();                        // all-thread acquire before reading new h
    }
  }
}

extern "C" void kernel_launch(void* const* d_in, const int* in_sizes, int n_in,
                              void* d_out, int out_size, void* d_ws, size_t ws_size,
                              hipStream_t stream){
  const float* text=(const float*)d_in[0];
  const int*  vid =(const int*) d_in[1];
  const int*  aid =(const int*) d_in[2];
  const float* vemb=(const float*)d_in[3];
  const float* aemb=(const float*)d_in[4];
  const float* egw =(const float*)d_in[5];
  const float* Wih =(const float*)d_in[6];
  const float* Whh =(const float*)d_in[7];
  const float* bih =(const float*)d_in[8];
  const float* bhh =(const float*)d_in[9];
  const float* lng =(const float*)d_in[10];
  const float* lnb =(const float*)d_in[11];
  const float* vW  =(const float*)d_in[20];
  const float* vb  =(const float*)d_in[21];
  float* out = (float*)d_out;

  // ---- workspace layout (~60 MB, under proven-safe 91 MB) ----
  float* W = (float*)d_ws;
  const size_t S = (size_t)B*D;
  float* att_t = W;
  float* fcross= att_t + S;
  float* cbuf  = fcross + S;             // reused as barrier flag array (768 ints)
  float* bsum  = cbuf + S;               // G4
  float* fb    = bsum + G4;              // D
  unsigned short* Wcat = (unsigned short*)(fb + D);      // G4*KCAT
  unsigned short* WcB  = Wcat + (size_t)G4*KCAT;         // D*KC
  unsigned short* catAB= WcB + (size_t)D*KC;             // B*KC
  unsigned short* hA0  = catAB + (size_t)B*KC;           // S
  unsigned short* hA1  = hA0 + S;                        // S
  bf16*  shift = (bf16*)(hA1 + S);                       // BN*D
  int* bar = (int*)cbuf;

  prep_weights<<<G4,256,0,stream>>>(Wih,Whh,bih,bhh,Wcat,bsum);
  prep_fcross<<<D,256,0,stream>>>(vW,vb,WcB,fb);
  egce_fused<<<B,256,0,stream>>>(text,vid,aid,vemb,aemb,egw,att_t,catAB);
  fcross_mfma<<<dim3(12,16),256,0,stream>>>(catAB,WcB,fb,fcross);
  fuse_ln<<<BN,256,0,stream>>>(text,att_t,fcross,lng,lnb,shift);
  zero_bar<<<3,256,0,stream>>>(bar);

  lstm_persist<<<768,256,0,stream>>>((const unsigned short*)shift,Wcat,bsum,
                                     hA0,hA1,text,att_t,out,bar);
}

// Round 5
// 1234.389 us; speedup vs baseline: 5.0164x; 5.0164x over previous
//
#include <hip/hip_runtime.h>
#include <hip/hip_bf16.h>
#include <math.h>

#define B 512
#define N 50
#define D 768
#define G4 3072
#define KCAT 1536       // concat K for fused step GEMM: [Whh | Wih]
#define BN (B*N)        // 25600
#define FLAT (N*D)      // 38400
#define KC 1536         // fcross K (vsum|asum concat)
#define CCH 6400        // floats per egce chunk = 128 channels x 50

typedef __hip_bfloat16 bf16;
typedef short short8 __attribute__((ext_vector_type(8)));
typedef float floatx4 __attribute__((ext_vector_type(4)));

__device__ __forceinline__ float sigf(float x){ return 1.0f/(1.0f+expf(-x)); }
__device__ __forceinline__ float u2f(unsigned short u){ return __uint_as_float(((unsigned int)u)<<16); }
__device__ __forceinline__ unsigned short f2u(float f){ bf16 h=__float2bfloat16(f); return *(unsigned short*)&h; }

// ---- EGCE fused, float4 edition: vectorized GAP + gates + gated v/a sums -----------
// All global loads are float4 (row-safe: every 4-aligned flat index j stays within one
// 768-float embedding row since 768%4==0). One block per batch.
__global__ __launch_bounds__(256) void egce_fused(
    const float* __restrict__ text, const int* __restrict__ vid, const int* __restrict__ aid,
    const float* __restrict__ vemb, const float* __restrict__ aemb, const float* __restrict__ egw,
    float* __restrict__ att_t, unsigned short* __restrict__ catAB){
  __shared__ float buf[CCH];
  __shared__ float gt[D+2], gv[D+2], ga[D+2];
  __shared__ float attvS[D], attaS[D];
  __shared__ int vidS[N], aidS[N];
  int b=blockIdx.x, tid=threadIdx.x;
  if(tid<N){ vidS[tid]=vid[b*N+tid]; aidS[tid]=aid[b*N+tid]; }
  if(tid==0){ gt[0]=gv[0]=ga[0]=0.f; gt[D+1]=gv[D+1]=ga[D+1]=0.f; }
  __syncthreads();
  const float4* tb4 = (const float4*)(text + (size_t)b*FLAT);
  for(int c=0;c<6;c++){
    int j0=c*CCH;
    for(int i=tid;i<1600;i+=256) ((float4*)buf)[i] = tb4[c*1600+i];
    __syncthreads();
    if(tid<128){ float s=0.f; for(int p=0;p<50;p++) s+=buf[tid*50+p]; gt[c*128+tid+1]=s*(1.f/50.f); }
    __syncthreads();
    for(int i=tid;i<1600;i+=256){
      int j=j0+i*4; int n=j/D, d=j-n*D;
      float4 v=*(const float4*)&vemb[(size_t)vidS[n]*D+d];
      v.x=fmaxf(v.x,0.f); v.y=fmaxf(v.y,0.f); v.z=fmaxf(v.z,0.f); v.w=fmaxf(v.w,0.f);
      ((float4*)buf)[i]=v;
    }
    __syncthreads();
    if(tid<128){ float s=0.f; for(int p=0;p<50;p++) s+=buf[tid*50+p]; gv[c*128+tid+1]=s*(1.f/50.f); }
    __syncthreads();
    for(int i=tid;i<1600;i+=256){
      int j=j0+i*4; int n=j/D, d=j-n*D;
      ((float4*)buf)[i]=*(const float4*)&aemb[(size_t)aidS[n]*D+d];
    }
    __syncthreads();
    if(tid<128){ float s=0.f; for(int p=0;p<50;p++) s+=buf[tid*50+p]; ga[c*128+tid+1]=s*(1.f/50.f); }
    __syncthreads();
  }
  float w0=egw[0],w1=egw[1],w2=egw[2];
  for(int ch=tid;ch<D;ch+=256){
    att_t[(size_t)b*D+ch]=sigf(w0*gt[ch]+w1*gt[ch+1]+w2*gt[ch+2]);
    attvS[ch]=sigf(w0*gv[ch]+w1*gv[ch+1]+w2*gv[ch+2]);
    attaS[ch]=sigf(w0*ga[ch]+w1*ga[ch+1]+w2*ga[ch+2]);
  }
  __syncthreads();
  // ---- gated sums over n, float4 per thread (threads 0..191 own d = 4*tid..+3) ----
  if(tid<192){
    float vax=0,vay=0,vaz=0,vaw=0, aax=0,aay=0,aaz=0,aaw=0;
    int d0=tid*4;
    for(int n=0;n<N;n++){
      int idv=vidS[n], ida=aidS[n];
      float4 v=*(const float4*)&vemb[(size_t)idv*D+d0];
      float4 a=*(const float4*)&aemb[(size_t)ida*D+d0];
      int base=n*D+d0;
      int c0=base/50, c1=(base+1)/50, c2=(base+2)/50, c3=(base+3)/50;
      vax+=fmaxf(v.x,0.f)*attvS[c0]; vay+=fmaxf(v.y,0.f)*attvS[c1];
      vaz+=fmaxf(v.z,0.f)*attvS[c2]; vaw+=fmaxf(v.w,0.f)*attvS[c3];
      aax+=a.x*attaS[c0]; aay+=a.y*attaS[c1]; aaz+=a.z*attaS[c2]; aaw+=a.w*attaS[c3];
    }
    unsigned short* cb=&catAB[(size_t)b*KC];
    cb[d0]=f2u(vax); cb[d0+1]=f2u(vay); cb[d0+2]=f2u(vaz); cb[d0+3]=f2u(vaw);
    cb[D+d0]=f2u(aax); cb[D+d0+1]=f2u(aay); cb[D+d0+2]=f2u(aaz); cb[D+d0+3]=f2u(aaw);
  }
}

// ---- weight prep: concat [Whh | Wih] rows, gate-interleave n'=dg*4+g (bf16) --------
__global__ __launch_bounds__(256) void prep_weights(
    const float* __restrict__ Wih, const float* __restrict__ Whh,
    const float* __restrict__ bih, const float* __restrict__ bhh,
    unsigned short* __restrict__ Wcat, float* __restrict__ bsum){
  int np = blockIdx.x;
  int dg = np>>2, g = np&3;
  size_t src = (size_t)(g*D+dg)*D;
  for(int k=threadIdx.x;k<D;k+=256){
    Wcat[(size_t)np*KCAT + k]     = f2u(Whh[src+k]);
    Wcat[(size_t)np*KCAT + D + k] = f2u(Wih[src+k]);
  }
  if(threadIdx.x==0) bsum[np] = bih[g*D+dg] + bhh[g*D+dg];
}

// ---- fcross weight prep ------------------------------------------------------------
__global__ __launch_bounds__(256) void prep_fcross(
    const float* __restrict__ vW, const float* __restrict__ vb,
    unsigned short* __restrict__ WcB, float* __restrict__ fb){
  int n = blockIdx.x;
  const float* W0 = vW; const float* W1 = vW + D*D; const float* W2 = vW + 2*D*D;
  for(int k=threadIdx.x;k<D;k+=256){
    WcB[(size_t)n*KC + k]     = f2u(W0[(size_t)n*D+k]);
    WcB[(size_t)n*KC + D + k] = f2u(W1[(size_t)n*D+k] + W2[(size_t)n*D+k]);
  }
  if(threadIdx.x==0) fb[n] = 50.f*(vb[n]+vb[D+n]+vb[2*D+n]);
}

// ---- fcross MFMA -------------------------------------------------------------------
__global__ __launch_bounds__(256) void fcross_mfma(
    const unsigned short* __restrict__ catAB, const unsigned short* __restrict__ WcB,
    const float* __restrict__ fb, float* __restrict__ fcross){
  __shared__ unsigned short Ash[32*40];
  __shared__ unsigned short Bsh[64*40];
  int tid=threadIdx.x;
  int bx=blockIdx.x, by=blockIdx.y;
  int lane=tid&63, w=tid>>6;
  int l15=lane&15, lq=lane>>4;
  int arow=tid>>3, aseg=(tid&7)*4;
  int brow=tid>>2, bseg=(tid&3)*8;
  floatx4 acc0={},acc1={};
  const unsigned short* aG = catAB + (size_t)(by*32 + arow)*KC + aseg;
  const unsigned short* bG = WcB   + (size_t)(bx*64 + brow)*KC + bseg;
  for(int k0=0;k0<KC;k0+=32){
    *(uint2*)&Ash[arow*40 + aseg] = *(const uint2*)(aG + k0);
    *(uint4*)&Bsh[brow*40 + bseg] = *(const uint4*)(bG + k0);
    __syncthreads();
    short8 a0=*(const short8*)&Ash[l15*40 + lq*8];
    short8 a1=*(const short8*)&Ash[(16+l15)*40 + lq*8];
    short8 bb=*(const short8*)&Bsh[(w*16 + l15)*40 + lq*8];
    acc0=__builtin_amdgcn_mfma_f32_16x16x32_bf16(a0,bb,acc0,0,0,0);
    acc1=__builtin_amdgcn_mfma_f32_16x16x32_bf16(a1,bb,acc1,0,0,0);
    __syncthreads();
  }
  int n = bx*64 + w*16 + l15;
  float bias = fb[n];
  #pragma unroll
  for(int r=0;r<4;r++){
    int m0 = by*32 + lq*4 + r;
    fcross[(size_t)m0*D + n]      = (acc0[r] + bias)*(1.f/3.f);
    fcross[(size_t)(m0+16)*D + n] = (acc1[r] + bias)*(1.f/3.f);
  }
}

// ---- fused pre-LN + LayerNorm ------------------------------------------------------
__global__ __launch_bounds__(256) void fuse_ln(
    const float* __restrict__ text, const float* __restrict__ att_t,
    const float* __restrict__ fcross, const float* __restrict__ lng,
    const float* __restrict__ lnb, bf16* __restrict__ shift){
  int row = blockIdx.x;
  int b = row/N, n = row - b*N;
  int tid=threadIdx.x;
  float v[3];
  for(int q=0;q<3;q++){
    int d=q*256+tid;
    int ch=(n*D+d)/50;
    v[q] = text[(size_t)row*D+d]*att_t[(size_t)b*D+ch] + fcross[(size_t)b*D+d];
  }
  __shared__ float red[256];
  red[tid]=v[0]+v[1]+v[2]; __syncthreads();
  for(int st=128;st>0;st>>=1){ if(tid<st) red[tid]+=red[tid+st]; __syncthreads(); }
  float m = red[0]*(1.f/768.f);
  __syncthreads();
  float s2=0.f;
  for(int q=0;q<3;q++){ float dl=v[q]-m; s2+=dl*dl; }
  red[tid]=s2; __syncthreads();
  for(int st=128;st>0;st>>=1){ if(tid<st) red[tid]+=red[tid+st]; __syncthreads(); }
  float var = red[0]*(1.f/768.f);
  float rs = 1.f/sqrtf(var+1e-5f);
  for(int q=0;q<3;q++){
    int d=q*256+tid;
    shift[(size_t)row*D+d]=__float2bfloat16((v[q]-m)*rs*lng[d]+lnb[d]);
  }
}

// ---- fused LSTM step: gates = [h|x]@[Whh|Wih]^T + b, one launch per timestep -------
// 1-D grid 768 blocks (3/CU), XCD-bijective swizzle. Tile 32m x 64n'. BK=64.
// TRIPLE-buffered LDS, prefetch distance 2: loads for tile k+2 issue at iter k,
// vmcnt-waited only at iter k+1's ds_write -> 2x latency window vs dbuf.
// LDS 45KB -> 3 blocks/CU. Proven pad-40 maps + operand-swapped epilogue unchanged.
__global__ __launch_bounds__(256) void lstm_fused(
    const unsigned short* __restrict__ shift, const unsigned short* __restrict__ Wcat,
    const float* __restrict__ bsum, const unsigned short* __restrict__ hprev,
    unsigned short* __restrict__ hnext, float* __restrict__ cbuf,
    const float* __restrict__ text, const float* __restrict__ att_t,
    float* __restrict__ out, int t){
  __shared__ unsigned short Ab[3][64*40];    // [buf][kh*32+row][40]  (15KB)
  __shared__ unsigned short Bb[3][128*40];   // [buf][kh*64+row][40]  (30KB)
  const int tid=threadIdx.x;
  const int id = blockIdx.x;
  const int xcd = id & 7;
  const int j = id >> 3;
  const int bx = xcd*6 + (j>>4);
  const int by = j & 15;
  const int lane=tid&63, w=tid>>6, l15=lane&15, lq=lane>>4;

  // ---- staging maps (uint4 = 8 shorts per slot) ----
  const int sra = tid>>2, ca=(tid&3)*8;
  const int arow = sra&31, ah = sra>>5;
  const int dA = sra*40 + ca;
  const int b_a = by*32 + arow;
  const unsigned short* hThr = hprev + (size_t)b_a*D + ah*32 + ca;
  const unsigned short* xThr = shift + ((size_t)b_a*N + t)*D + ah*32 + ca;

  const int sr0 = tid>>2,        c0=(tid&3)*8;
  const int sr1 = (tid+256)>>2,  c1=(tid&3)*8;
  const int br0 = sr0&63, bh0 = sr0>>6;
  const int br1 = sr1&63, bh1 = sr1>>6;
  const unsigned short* bThr0 = Wcat + (size_t)(bx*64+br0)*KCAT + bh0*32 + c0;
  const unsigned short* bThr1 = Wcat + (size_t)(bx*64+br1)*KCAT + bh1*32 + c1;
  const int dB0 = sr0*40 + c0, dB1 = sr1*40 + c1;

  const int kbase  = t ? 0 : 768;              // t=0: h is zero -> skip Whh half
  const int nIters = t ? 24 : 12;

  floatx4 acc0={}, acc1={};
  uint4 rA, rB0, rB1;

  // prologue: stage tile0 into buf0; issue tile1 into regs
  {
    const unsigned short* ap = (kbase<768) ? (hThr + kbase) : (xThr + (kbase-768));
    rA  = *(const uint4*)ap;
    rB0 = *(const uint4*)(bThr0 + kbase);
    rB1 = *(const uint4*)(bThr1 + kbase);
    *(uint4*)&Ab[0][dA]  = rA;
    *(uint4*)&Bb[0][dB0] = rB0;
    *(uint4*)&Bb[0][dB1] = rB1;
  }
  {
    int kg = kbase + 64;
    const unsigned short* ap = (kg<768) ? (hThr + kg) : (xThr + (kg-768));
    rA  = *(const uint4*)ap;
    rB0 = *(const uint4*)(bThr0 + kg);
    rB1 = *(const uint4*)(bThr1 + kg);
  }
  __syncthreads();

  int cur=0, nxt=1, thr=2;   // rotating buffer indices (static under unroll 3)
  #pragma unroll 3
  for(int it=0; it<nIters; ++it){
    // (1) write tile it+1 (regs loaded at it-1 / prologue) into buf[nxt]
    if(it+1 < nIters){
      *(uint4*)&Ab[nxt][dA]  = rA;
      *(uint4*)&Bb[nxt][dB0] = rB0;
      *(uint4*)&Bb[nxt][dB1] = rB1;
    }
    // (2) issue loads for tile it+2 (waited at iter it+1's ds_write)
    if(it+2 < nIters){
      int kg = kbase + (it+2)*64;
      const unsigned short* ap = (kg<768) ? (hThr + kg) : (xThr + (kg-768));
      rA  = *(const uint4*)ap;
      rB0 = *(const uint4*)(bThr0 + kg);
      rB1 = *(const uint4*)(bThr1 + kg);
    }
    // (3) compute tile it from buf[cur]
    short8 Wf0 = *(const short8*)&Bb[cur][(w*16+l15)*40 + lq*8];
    short8 Wf1 = *(const short8*)&Bb[cur][(64 + w*16+l15)*40 + lq*8];
    short8 X00 = *(const short8*)&Ab[cur][(l15)*40 + lq*8];
    short8 X10 = *(const short8*)&Ab[cur][(16+l15)*40 + lq*8];
    short8 X01 = *(const short8*)&Ab[cur][(32+l15)*40 + lq*8];
    short8 X11 = *(const short8*)&Ab[cur][(48+l15)*40 + lq*8];
    acc0 = __builtin_amdgcn_mfma_f32_16x16x32_bf16(Wf0, X00, acc0, 0,0,0);
    acc1 = __builtin_amdgcn_mfma_f32_16x16x32_bf16(Wf0, X10, acc1, 0,0,0);
    acc0 = __builtin_amdgcn_mfma_f32_16x16x32_bf16(Wf1, X01, acc0, 0,0,0);
    acc1 = __builtin_amdgcn_mfma_f32_16x16x32_bf16(Wf1, X11, acc1, 0,0,0);
    __syncthreads();
    int tmp=cur; cur=nxt; nxt=thr; thr=tmp;
  }

  // ---- epilogue: gates -> c,h ; fused residual out-write -----------------------
  const int nb = bx*64 + w*16 + lq*4;
  const int dg = nb>>2;
  floatx4 bs = *(const floatx4*)&bsum[nb];
  #pragma unroll
  for(int mf=0; mf<2; ++mf){
    floatx4 a = mf ? acc1 : acc0;
    int b = by*32 + mf*16 + l15;
    float gi=a[0]+bs[0], gf=a[1]+bs[1], gg=a[2]+bs[2], go=a[3]+bs[3];
    float co = t ? cbuf[(size_t)b*D+dg] : 0.f;
    float cn = sigf(gf)*co + sigf(gi)*tanhf(gg);
    float hn = sigf(go)*tanhf(cn);
    cbuf[(size_t)b*D+dg] = cn;
    hnext[(size_t)b*D+dg] = f2u(hn);
    int ch = (t*D+dg)/50;
    size_t oi = ((size_t)b*N + t)*D + dg;
    out[oi] = hn + text[oi]*att_t[(size_t)b*D+ch];
  }
}

extern "C" void kernel_launch(void* const* d_in, const int* in_sizes, int n_in,
                              void* d_out, int out_size, void* d_ws, size_t ws_size,
                              hipStream_t stream){
  const float* text=(const float*)d_in[0];
  const int*  vid =(const int*) d_in[1];
  const int*  aid =(const int*) d_in[2];
  const float* vemb=(const float*)d_in[3];
  const float* aemb=(const float*)d_in[4];
  const float* egw =(const float*)d_in[5];
  const float* Wih =(const float*)d_in[6];
  const float* Whh =(const float*)d_in[7];
  const float* bih =(const float*)d_in[8];
  const float* bhh =(const float*)d_in[9];
  const float* lng =(const float*)d_in[10];
  const float* lnb =(const float*)d_in[11];
  const float* vW  =(const float*)d_in[20];
  const float* vb  =(const float*)d_in[21];
  float* out = (float*)d_out;

  // ---- workspace layout (~60 MB, under proven-safe 91 MB) ----
  float* W = (float*)d_ws;
  const size_t S = (size_t)B*D;
  float* att_t = W;
  float* fcross= att_t + S;
  float* cbuf  = fcross + S;
  float* bsum  = cbuf + S;               // G4
  float* fb    = bsum + G4;              // D
  unsigned short* Wcat = (unsigned short*)(fb + D);      // G4*KCAT
  unsigned short* WcB  = Wcat + (size_t)G4*KCAT;         // D*KC
  unsigned short* catAB= WcB + (size_t)D*KC;             // B*KC
  unsigned short* hA0  = catAB + (size_t)B*KC;           // S
  unsigned short* hA1  = hA0 + S;                        // S
  bf16*  shift = (bf16*)(hA1 + S);                       // BN*D

  prep_weights<<<G4,256,0,stream>>>(Wih,Whh,bih,bhh,Wcat,bsum);
  prep_fcross<<<D,256,0,stream>>>(vW,vb,WcB,fb);
  egce_fused<<<B,256,0,stream>>>(text,vid,aid,vemb,aemb,egw,att_t,catAB);
  fcross_mfma<<<dim3(12,16),256,0,stream>>>(catAB,WcB,fb,fcross);
  fuse_ln<<<BN,256,0,stream>>>(text,att_t,fcross,lng,lnb,shift);

  for(int t=0;t<N;t++){
    unsigned short* hp = (t&1)? hA1 : hA0;
    unsigned short* hn = (t&1)? hA0 : hA1;
    lstm_fused<<<768,256,0,stream>>>((const unsigned short*)shift,Wcat,bsum,
                                     hp,hn,cbuf,text,att_t,out,t);
  }
}